// Round 2
// baseline (253.256 us; speedup 1.0000x reference)
//
#include <hip/hip_runtime.h>

// VQ-VAE codebook quantization forward, bit-replicating the numpy fp32
// reference semantics (ref=np evaluates in float32; its quantized argmin is
// the spec — an exact f64 argmin mismatches ~100/131072 positions):
//   cb_sqr/x_sqr: numpy pairwise_sum n=64 path (8 accumulators of rounded
//                 squares, ((r0+r1)+(r2+r3))+((r4+r5)+(r6+r7))), no FMA.
//   dot:          BLAS sgemm style — sequential FMA over d, one accumulator.
//   dist:         fl(fl(cb_sqr[k] + x_sqr) - 2*dot)   (2*dot exact)
//   argmin:       first-min (strict <, k ascending) like np.argmin.

#define KCODES 512
#define DDIM 64
#define HWSZ 4096            // H*W
#define NPOS 131072          // B*H*W
#define OUT2_OFF 8388608     // B*D*H*W

// numpy pairwise_sum (n=64 branch) of rounded squares a[i]*a[i], fp32, no fma.
__device__ __forceinline__ float np_sumsq64(const float* __restrict__ a) {
#pragma clang fp contract(off)
    float r0 = a[0] * a[0], r1 = a[1] * a[1], r2 = a[2] * a[2], r3 = a[3] * a[3];
    float r4 = a[4] * a[4], r5 = a[5] * a[5], r6 = a[6] * a[6], r7 = a[7] * a[7];
#pragma unroll
    for (int i = 8; i < 64; i += 8) {
        r0 += a[i + 0] * a[i + 0];
        r1 += a[i + 1] * a[i + 1];
        r2 += a[i + 2] * a[i + 2];
        r3 += a[i + 3] * a[i + 3];
        r4 += a[i + 4] * a[i + 4];
        r5 += a[i + 5] * a[i + 5];
        r6 += a[i + 6] * a[i + 6];
        r7 += a[i + 7] * a[i + 7];
    }
    return ((r0 + r1) + (r2 + r3)) + ((r4 + r5) + (r6 + r7));
}

__global__ __launch_bounds__(256) void vq_fp32exact_argmin(
    const float* __restrict__ z, const float* __restrict__ cb,
    float* __restrict__ out)
{
#pragma clang fp contract(off)
    __shared__ float s_cbsqr[KCODES];
    const int tid = threadIdx.x;

    for (int k = tid; k < KCODES; k += 256)
        s_cbsqr[k] = np_sumsq64(cb + k * DDIM);
    __syncthreads();

    const int n = blockIdx.x * 256 + tid;      // grid = NPOS/256
    const int b = n >> 12;
    const int hw = n & 4095;
    const long base = (long)b * (DDIM * HWSZ) + hw;

    // Gather x (NCHW): lanes differ only in hw -> coalesced per d.
    float x[DDIM];
#pragma unroll
    for (int d = 0; d < DDIM; ++d) x[d] = z[base + (long)d * HWSZ];

    const float xsqr = np_sumsq64(x);

    float best = 3.4e38f;
    int idx = 0;
    for (int k = 0; k < KCODES; k += 4) {       // 4 codes in flight (ILP)
        const float* c = cb + k * DDIM;          // wave-uniform address
        float d0 = 0.f, d1 = 0.f, d2 = 0.f, d3 = 0.f;
#pragma unroll
        for (int d = 0; d < DDIM; ++d) {
            d0 = fmaf(x[d], c[d], d0);
            d1 = fmaf(x[d], c[d + DDIM], d1);
            d2 = fmaf(x[d], c[d + 2 * DDIM], d2);
            d3 = fmaf(x[d], c[d + 3 * DDIM], d3);
        }
        float t0 = s_cbsqr[k]     + xsqr;  float e0 = t0 - 2.0f * d0;
        float t1 = s_cbsqr[k + 1] + xsqr;  float e1 = t1 - 2.0f * d1;
        float t2 = s_cbsqr[k + 2] + xsqr;  float e2 = t2 - 2.0f * d2;
        float t3 = s_cbsqr[k + 3] + xsqr;  float e3 = t3 - 2.0f * d3;
        if (e0 < best) { best = e0; idx = k; }
        if (e1 < best) { best = e1; idx = k + 1; }
        if (e2 < best) { best = e2; idx = k + 2; }
        if (e3 < best) { best = e3; idx = k + 3; }
    }

    // Scatter selected code to both outputs (NCHW).
    const float4* crow = (const float4*)(cb + idx * DDIM);
    float* o0 = out + base;
    float* o1 = o0 + OUT2_OFF;
#pragma unroll
    for (int q = 0; q < DDIM / 4; ++q) {
        float4 v = crow[q];
        const long d0 = (long)(q * 4) * HWSZ;
        o0[d0]            = v.x; o0[d0 + HWSZ]     = v.y;
        o0[d0 + 2 * HWSZ] = v.z; o0[d0 + 3 * HWSZ] = v.w;
        o1[d0]            = v.x; o1[d0 + HWSZ]     = v.y;
        o1[d0 + 2 * HWSZ] = v.z; o1[d0 + 3 * HWSZ] = v.w;
    }
}

extern "C" void kernel_launch(void* const* d_in, const int* in_sizes, int n_in,
                              void* d_out, int out_size, void* d_ws, size_t ws_size,
                              hipStream_t stream) {
    const float* z  = (const float*)d_in[0];   // [32,64,64,64] fp32
    const float* cb = (const float*)d_in[1];   // [512,64] fp32
    float* out = (float*)d_out;                // 2 * 8388608 fp32
    vq_fp32exact_argmin<<<NPOS / 256, 256, 0, stream>>>(z, cb, out);
}